// Round 12
// baseline (70.778 us; speedup 1.0000x reference)
//
#include <hip/hip_runtime.h>
#include <hip/hip_bf16.h>
#include <cstring>

// Species-routed per-atom 3-layer MLP via MFMA, round 12.
// = R11 with layer-1 X loads restructured: desc row starts are misaligned by
// R = (atom*39) mod 4 dwords, and atom mod 4 == wid, so R is a COMPILE-TIME
// constant per wave ({0,3,2,1}[wid]). Each wave runs layer1_run<R>: loads
// 16B-ALIGNED dwordx4 windows (4-6 per row instead of 16 scalar dword loads
// -> ~3x fewer VMEM instructions) and extracts the k-window with static
// register selects. Depth-2 rolling prefetch (named A/B, rule-#20 safe).
// In-bounds by construction: R>=2 extra chunks only occur for wid 1/2
// (atom <= 254); wid 3 (atom 255) touches at most rbase+38 = last element.

#define NN    4096
#define AA    256
#define DIN   39
#define HH    50
#define ATILE 4
#define NTILE 64
#define XSTR  72                   // H1 LDS row stride (shorts): 144 B
#define WFS   (2 * 2 * 4 * 64 * 8) // shorts per species, frag layout (16 KB)
#define RD    (AA * DIN)           // dwords per n-row of desc (9984)

typedef __attribute__((ext_vector_type(8))) short bf16x8;
typedef __attribute__((ext_vector_type(4))) float f32x4;

__device__ __forceinline__ float fast_silu(float x) {
    return x * __builtin_amdgcn_rcpf(1.0f + __expf(-x));
}
__device__ __forceinline__ unsigned pack_bf2(float a, float b) {
    __hip_bfloat162 h = __float22bfloat162_rn(float2{a, b});
    unsigned u; memcpy(&u, &h, 4); return u;
}

// ---------------- prep: weights -> per-lane frag layout (unchanged) --------
// Wf[s] dword d = [L][ks][mt][lane][j2]: wcol=16*mt+(lane&15),
// k=ks*32+8*(lane>>4)+2*j2(+1); zero outside valid ranges.
// Bp[s][0..3][64] f32 = b1, b2, w3, b3(broadcast), zero-padded.
__global__ __launch_bounds__(256) void prep_weights(
    const float* __restrict__ W1, const float* __restrict__ b1,
    const float* __restrict__ W2, const float* __restrict__ b2,
    const float* __restrict__ W3, const float* __restrict__ b3,
    unsigned short* __restrict__ Wf, float* __restrict__ Bp)
{
    const int s = blockIdx.x >> 3;
    const int c = blockIdx.x & 7;
    const int t = threadIdx.x;
    const float* __restrict__ w1g = W1 + s * (DIN * HH);
    const float* __restrict__ w2g = W2 + s * (HH * HH);
    unsigned* __restrict__ outw = (unsigned*)(Wf + (size_t)s * WFS);

    #pragma unroll
    for (int i = 0; i < 2; ++i) {
        const int d    = c * 512 + i * 256 + t;
        const int j2   = d & 3;
        const int lane = (d >> 2) & 63;
        const int mt   = (d >> 8) & 3;
        const int ks   = (d >> 10) & 1;
        const int L    = (d >> 11) & 1;
        const int col  = 16 * mt + (lane & 15);
        const int k0   = ks * 32 + 8 * (lane >> 4) + 2 * j2;
        const int k1   = k0 + 1;
        float v0 = 0.f, v1 = 0.f;
        if (col < HH) {
            if (L == 0) {
                if (k0 < DIN) v0 = w1g[k0 * HH + col];
                if (k1 < DIN) v1 = w1g[k1 * HH + col];
            } else {
                if (k0 < HH)  v0 = w2g[k0 * HH + col];
                if (k1 < HH)  v1 = w2g[k1 * HH + col];
            }
        }
        outw[d] = pack_bf2(v0, v1);
    }
    if (c == 0 && t < 64) {
        float* bp = Bp + s * 256;
        const bool v = t < HH;
        bp[t]       = v ? b1[s * HH + t] : 0.0f;
        bp[64 + t]  = v ? b2[s * HH + t] : 0.0f;
        bp[128 + t] = v ? W3[s * HH + t] : 0.0f;
        bp[192 + t] = b3[s];
    }
}

// ---------------- layer 1, one instantiation per wave rotation R ----------
// Loads aligned dwordx4 windows; extracts k-values with STATIC indices.
//   xf0: dwords rbase+8lg .. +8lg+7  = window idx R..R+7 of xw (12 dwords)
//   xf1: dwords rbase+32 .. +38 (+dup(38)) = idx R..R+6,R+6 of xz
// xw[2] only needed for R>=1; xz[2] only for R>=2 (atoms <= 254 then).
template<int R>
__device__ __forceinline__ void layer1_run(
    const float* __restrict__ desc, size_t arow, int n0, int lg, int lr,
    int wbase, const bf16x8 (&w1f)[2][4], const f32x4 (&b1q)[4],
    unsigned short* __restrict__ Hb)
{
    f32x4 xwA[3], xzA[3], xwB[3], xzB[3];

    auto loadrow = [&](int nt, f32x4 (&xw)[3], f32x4 (&xz)[3]) {
        const size_t rb = (size_t)(n0 + 16 * nt + lr) * RD + arow; // dwords
        const float* A = desc + (rb - (size_t)R);                  // 16B-aligned
        xw[0] = *(const f32x4*)(A + 8 * lg);
        xw[1] = *(const f32x4*)(A + 8 * lg + 4);
        if constexpr (R >= 1) xw[2] = *(const f32x4*)(A + 8 * lg + 8);
        else                  xw[2] = f32x4{0.f, 0.f, 0.f, 0.f};
        xz[0] = *(const f32x4*)(A + 32);
        xz[1] = *(const f32x4*)(A + 36);
        if constexpr (R >= 2) xz[2] = *(const f32x4*)(A + 40);
        else                  xz[2] = f32x4{0.f, 0.f, 0.f, 0.f};
    };

    auto compute = [&](int nt, const f32x4 (&xw)[3], const f32x4 (&xz)[3]) {
        const float* pw = reinterpret_cast<const float*>(&xw[0]);
        const float* pz = reinterpret_cast<const float*>(&xz[0]);
        unsigned u[4];
        #pragma unroll
        for (int i = 0; i < 4; ++i)
            u[i] = pack_bf2(pw[R + 2 * i], pw[R + 2 * i + 1]);
        bf16x8 xf0; memcpy(&xf0, u, 16);
        u[0] = pack_bf2(pz[R + 0], pz[R + 1]);
        u[1] = pack_bf2(pz[R + 2], pz[R + 3]);
        u[2] = pack_bf2(pz[R + 4], pz[R + 5]);
        u[3] = pack_bf2(pz[R + 6], pz[R + 6]);   // k=39 slot: dc (zero weight)
        bf16x8 xf1; memcpy(&xf1, u, 16);

        #pragma unroll
        for (int mt = 0; mt < 4; ++mt) {
            f32x4 c = f32x4{0.f, 0.f, 0.f, 0.f};
            c = __builtin_amdgcn_mfma_f32_16x16x32_bf16(w1f[0][mt], xf0, c, 0, 0, 0);
            c = __builtin_amdgcn_mfma_f32_16x16x32_bf16(w1f[1][mt], xf1, c, 0, 0, 0);
            const unsigned h0 = pack_bf2(fast_silu(c[0] + b1q[mt][0]),
                                         fast_silu(c[1] + b1q[mt][1]));
            const unsigned h1 = pack_bf2(fast_silu(c[2] + b1q[mt][2]),
                                         fast_silu(c[3] + b1q[mt][3]));
            uint2 uu; uu.x = h0; uu.y = h1;
            *(uint2*)&Hb[(wbase + 16 * nt + lr) * XSTR + 16 * mt + 4 * lg] = uu;
        }
    };

    // depth-2 rolling prefetch, all names static (rule #20)
    loadrow(0, xwA, xzA);
    loadrow(1, xwB, xzB);
    compute(0, xwA, xzA); loadrow(2, xwA, xzA);
    compute(1, xwB, xzB); loadrow(3, xwB, xzB);
    compute(2, xwA, xzA);
    compute(3, xwB, xzB);
}

// ---------------- main kernel ----------------
__global__ __launch_bounds__(256, 4) void atomic_mlp_mfma(
    const float* __restrict__ desc,
    const int*   __restrict__ numbers,
    const unsigned short* __restrict__ Wf,
    const float* __restrict__ Bp,
    float*       __restrict__ out)
{
    __shared__ unsigned short Hb[ATILE * NTILE * XSTR];   // H1 only (36 KB)
    __shared__ float          Ob[ATILE * NTILE];          // outputs (1 KB)

    const int a0 = blockIdx.x * ATILE;
    const int n0 = blockIdx.y * NTILE;
    const int t  = threadIdx.x;
    const int lane = t & 63;
    const int lg   = lane >> 4;
    const int lr   = lane & 15;
    const int wid  = t >> 6;
    const int wbase = wid * NTILE;      // this wave's H1 row base (its atom)

    // wave-uniform species -> SGPR
    const int sw = __builtin_amdgcn_readfirstlane(numbers[a0 + wid]);
    const unsigned short* __restrict__ wfs = Wf + (size_t)sw * WFS;
    const float* __restrict__ bp = Bp + sw * 256;

    // ---- phase-1 working set: W1 A-frags + b1 (pinned into registers) ----
    bf16x8 w1f[2][4];
    #pragma unroll
    for (int ks = 0; ks < 2; ++ks)
        #pragma unroll
        for (int mt = 0; mt < 4; ++mt)
            w1f[ks][mt] = *(const bf16x8*)&wfs[((ks * 4 + mt) * 64 + lane) * 8];
    f32x4 b1q[4];
    #pragma unroll
    for (int mt = 0; mt < 4; ++mt)
        b1q[mt] = *(const f32x4*)&bp[16 * mt + 4 * lg];
    #pragma unroll
    for (int ks = 0; ks < 2; ++ks)
        #pragma unroll
        for (int mt = 0; mt < 4; ++mt)
            asm volatile("" : "+v"(w1f[ks][mt]));
    #pragma unroll
    for (int mt = 0; mt < 4; ++mt) asm volatile("" : "+v"(b1q[mt]));

    const float bias3 = bp[192];

    // ---- Layer 1: rotation R is a compile-time function of wid ----
    const size_t arow = (size_t)(a0 + wid) * DIN;
    switch (wid) {                       // wave-uniform branch
        case 0:  layer1_run<0>(desc, arow, n0, lg, lr, wbase, w1f, b1q, Hb); break;
        case 1:  layer1_run<3>(desc, arow, n0, lg, lr, wbase, w1f, b1q, Hb); break;
        case 2:  layer1_run<2>(desc, arow, n0, lg, lr, wbase, w1f, b1q, Hb); break;
        default: layer1_run<1>(desc, arow, n0, lg, lr, wbase, w1f, b1q, Hb); break;
    }

    // ---- phase-2 working set: W2 A-frags + b2 + w3 (pinned) ----
    bf16x8 w2f[2][4];
    #pragma unroll
    for (int ks = 0; ks < 2; ++ks)
        #pragma unroll
        for (int mt = 0; mt < 4; ++mt)
            w2f[ks][mt] = *(const bf16x8*)&wfs[((8 + ks * 4 + mt) * 64 + lane) * 8];
    f32x4 b2q[4], w3q[4];
    #pragma unroll
    for (int mt = 0; mt < 4; ++mt) {
        b2q[mt] = *(const f32x4*)&bp[64 + 16 * mt + 4 * lg];
        w3q[mt] = *(const f32x4*)&bp[128 + 16 * mt + 4 * lg];
    }
    #pragma unroll
    for (int ks = 0; ks < 2; ++ks)
        #pragma unroll
        for (int mt = 0; mt < 4; ++mt)
            asm volatile("" : "+v"(w2f[ks][mt]));
    #pragma unroll
    for (int mt = 0; mt < 4; ++mt) {
        asm volatile("" : "+v"(b2q[mt]));
        asm volatile("" : "+v"(w3q[mt]));
    }

    // ---- Layer 2 + 3: H1 frags from LDS (wave-private, no barrier) ----
    #pragma unroll
    for (int nt = 0; nt < 4; ++nt) {
        const int row = wbase + 16 * nt + lr;
        const bf16x8 hf0 = *(const bf16x8*)&Hb[row * XSTR + 8 * lg];
        const bf16x8 hf1 = *(const bf16x8*)&Hb[row * XSTR + 32 + 8 * lg];
        float p = 0.f;
        #pragma unroll
        for (int mt = 0; mt < 4; ++mt) {
            f32x4 c = f32x4{0.f, 0.f, 0.f, 0.f};
            c = __builtin_amdgcn_mfma_f32_16x16x32_bf16(w2f[0][mt], hf0, c, 0, 0, 0);
            c = __builtin_amdgcn_mfma_f32_16x16x32_bf16(w2f[1][mt], hf1, c, 0, 0, 0);
            p += fast_silu(c[0] + b2q[mt][0]) * w3q[mt][0];
            p += fast_silu(c[1] + b2q[mt][1]) * w3q[mt][1];
            p += fast_silu(c[2] + b2q[mt][2]) * w3q[mt][2];
            p += fast_silu(c[3] + b2q[mt][3]) * w3q[mt][3];
        }
        p += __shfl_xor(p, 16);             // reduce across the 4 lg groups
        p += __shfl_xor(p, 32);
        if (lg == 0) Ob[row] = p + bias3;
    }

    __syncthreads();   // Ob complete across waves

    // ---- cooperative out store: one float4 wave-store covers the block ----
    if (t < NTILE) {
        float4 o;
        o.x = Ob[0 * NTILE + t];
        o.y = Ob[1 * NTILE + t];
        o.z = Ob[2 * NTILE + t];
        o.w = Ob[3 * NTILE + t];
        *(float4*)&out[(size_t)(n0 + t) * AA + a0] = o;
    }
}

extern "C" void kernel_launch(void* const* d_in, const int* in_sizes, int n_in,
                              void* d_out, int out_size, void* d_ws, size_t ws_size,
                              hipStream_t stream) {
    const float* desc    = (const float*)d_in[0];
    const int*   numbers = (const int*)  d_in[1];
    const float* W1      = (const float*)d_in[2];
    const float* b1      = (const float*)d_in[3];
    const float* W2      = (const float*)d_in[4];
    const float* b2      = (const float*)d_in[5];
    const float* W3      = (const float*)d_in[6];
    const float* b3      = (const float*)d_in[7];
    float*       out     = (float*)d_out;

    unsigned short* Wf = (unsigned short*)d_ws;                  // 8*16384 B
    float*          Bp = (float*)((char*)d_ws + 8 * WFS * 2);    // 8*256 f32

    hipLaunchKernelGGL(prep_weights, dim3(64), dim3(256), 0, stream,
                       W1, b1, W2, b2, W3, b3, Wf, Bp);

    dim3 grid(AA / ATILE, NN / NTILE);
    hipLaunchKernelGGL(atomic_mlp_mfma, grid, dim3(256), 0, stream,
                       desc, numbers, Wf, Bp, out);
}